// Round 13
// baseline (216.918 us; speedup 1.0000x reference)
//
#include <hip/hip_runtime.h>

typedef unsigned short u16;
typedef unsigned int u32;
typedef short bf16x8 __attribute__((ext_vector_type(8)));
typedef float f32x4 __attribute__((ext_vector_type(4)));
typedef u32 u32x4 __attribute__((ext_vector_type(4)));

#define AS_GLOBAL __attribute__((address_space(1)))
#define AS_LDS __attribute__((address_space(3)))

__device__ __forceinline__ void async16(const void* g, void* l) {
  __builtin_amdgcn_global_load_lds((const AS_GLOBAL u32*)g, (AS_LDS u32*)l, 16, 0, 0);
}

__device__ __forceinline__ u16 f2bf(float f) {
  u32 u = __builtin_bit_cast(u32, f);
  u += 0x7FFFu + ((u >> 16) & 1u);   // RNE
  return (u16)(u >> 16);
}

__device__ __forceinline__ u32 pk2bf(float lo, float hi) {
  return __builtin_amdgcn_perm(__builtin_bit_cast(u32, hi),
                               __builtin_bit_cast(u32, lo), 0x07060302u);
}

__device__ __forceinline__ float fexp2(float x) {
#if __has_builtin(__builtin_amdgcn_exp2f)
  return __builtin_amdgcn_exp2f(x);
#else
  return exp2f(x);
#endif
}

// ---------------- Pass A: all four f32 -> bf16 converts in one launch ----------------
__global__ __launch_bounds__(256) void cvt_all(const float* __restrict__ x,
                                               const float* __restrict__ wq,
                                               const float* __restrict__ wk,
                                               const float* __restrict__ wv,
                                               u16* __restrict__ xb,
                                               u16* __restrict__ wb) {
  const int blk = blockIdx.x;
  const float* src;
  u16* dst;
  int i;
  if (blk < 8192) {
    src = x; dst = xb; i = blk * 256 + threadIdx.x;
  } else if (blk < 9216) {
    src = wq; dst = wb; i = (blk - 8192) * 256 + threadIdx.x;
  } else if (blk < 10240) {
    src = wk; dst = wb + 1048576; i = (blk - 9216) * 256 + threadIdx.x;
  } else {
    src = wv; dst = wb + 2097152; i = (blk - 10240) * 256 + threadIdx.x;
  }
  float4 f = reinterpret_cast<const float4*>(src)[i];
  ushort4 o;
  o.x = f2bf(f.x); o.y = f2bf(f.y); o.z = f2bf(f.z); o.w = f2bf(f.w);
  reinterpret_cast<ushort4*>(dst)[i] = o;
}

// ---------------- Pass B: QKV projection GEMM (C = X * W^T) ----------------
// ROUND-12 VERSION, KEPT (implied ~2 us better than r7 4-wave: total flat
// while attn worsened 1.8). 8 waves (512 thr), per-wave 64x32 output; BK=64,
// dbuf, one __syncthreads per k-tile, conflict-free chunk-XOR swizzle;
// wide-store epilogue via LDS, 4 x global_store_dwordx4 per thread.
// grid: x = m-tile (64), y = n-tile (8), z = matrix (3)
// z=0 (Q), z=1 (K): out [B][H][T][64]; z=2 (V): out TRANSPOSED [B][H][64][T]
__global__ __launch_bounds__(512, 4) void qkv_gemm(const u16* __restrict__ X,
                                                   const u16* __restrict__ W,
                                                   u16* __restrict__ O) {
  const int z = blockIdx.z;
  const u16* Wz = W + (size_t)z * (1024 * 1024);
  u16* Oz = O + (size_t)z * (8192 * 1024);

  // unified 64KB: SMEM[0..1] = A dbuf, SMEM[2..3] = B dbuf; epilogue reuses
  // flat region: wave w gets 2560 u16 at sm + w*2560 (needs 2304).
  __shared__ __align__(16) u16 SMEM[4][8192];

  const int t = threadIdx.x;
  const int lane = t & 63, w = t >> 6, quad = lane >> 4, lq = lane & 15;
  const int wm = (w >> 2) * 64, wn = (w & 3) * 32;
  const int sw = lq & 7;
  const size_t m0 = (size_t)blockIdx.x * 128;
  const int n0 = blockIdx.y * 128;

  // staging source offsets (u16 units): slot -> (row, pre-swizzled chunk);
  // 512 threads x 2 slots cover one 128x64 panel (1024 16B chunks)
  int off[2];
#pragma unroll
  for (int j = 0; j < 2; ++j) {
    const int s = j * 512 + t, row = s >> 3, c = (s & 7) ^ (row & 7);
    off[j] = row * 1024 + c * 8;
  }
  const u16* gA = X + m0 * 1024;
  const u16* gB = Wz + (size_t)n0 * 1024;

  f32x4 acc[4][2];
#pragma unroll
  for (int i = 0; i < 4; ++i)
#pragma unroll
    for (int j = 0; j < 2; ++j) acc[i][j] = f32x4{0.f, 0.f, 0.f, 0.f};

  // 4 gload_lds(16B)/thread stages one 128x64 A panel + 128x64 B panel
  auto stage = [&](int kt, int nb) {
    const u16* ga = gA + kt * 64;
    const u16* gb = gB + kt * 64;
#pragma unroll
    for (int j = 0; j < 2; ++j)
      async16(ga + off[j], &SMEM[nb][(j * 512 + t) * 8]);
#pragma unroll
    for (int j = 0; j < 2; ++j)
      async16(gb + off[j], &SMEM[2 + nb][(j * 512 + t) * 8]);
  };

  // prologue: stage tile 0 into buffer 0
  stage(0, 0);

  for (int kt = 0; kt < 16; ++kt) {
    const int cur = kt & 1;
    __syncthreads();                    // tile kt resident; buf[cur^1] free
    if (kt < 15) stage(kt + 1, cur ^ 1);

    bf16x8 Af[4][2], Bf[2][2];
#pragma unroll
    for (int ks = 0; ks < 2; ++ks) {
#pragma unroll
      for (int i = 0; i < 4; ++i)
        Af[i][ks] = *reinterpret_cast<const bf16x8*>(
            &SMEM[cur][(wm + i * 16 + lq) * 64 + ((ks * 4 + quad) ^ sw) * 8]);
#pragma unroll
      for (int j = 0; j < 2; ++j)
        Bf[j][ks] = *reinterpret_cast<const bf16x8*>(
            &SMEM[2 + cur][(wn + j * 16 + lq) * 64 + ((ks * 4 + quad) ^ sw) * 8]);
    }
#pragma unroll
    for (int i = 0; i < 4; ++i)
#pragma unroll
      for (int j = 0; j < 2; ++j) {
        acc[i][j] = __builtin_amdgcn_mfma_f32_16x16x32_bf16(Af[i][0], Bf[j][0], acc[i][j], 0, 0, 0);
        acc[i][j] = __builtin_amdgcn_mfma_f32_16x16x32_bf16(Af[i][1], Bf[j][1], acc[i][j], 0, 0, 0);
      }
  }

  // ---- wide-store epilogue (per-wave 64x32 tile) ----
  __syncthreads();                      // all LDS reads of the main loop done
  u16* ep = &SMEM[0][0] + w * 2560;     // wave-private region
  const size_t ms = m0 + wm;
  const size_t bb = ms >> 11, tt0 = ms & 2047;
  const int hh = (n0 + wn) >> 6, d0 = (n0 + wn) & 63;   // d0 in {0,32}
  if (z != 2) {
    // LDS layout [64 rows(m)][36]: col = local n (0..31)
#pragma unroll
    for (int i = 0; i < 4; ++i)
#pragma unroll
      for (int j = 0; j < 2; ++j)
#pragma unroll
        for (int r = 0; r < 4; ++r)
          ep[(i * 16 + quad * 4 + r) * 36 + j * 16 + lq] = f2bf(acc[i][j][r]);
    asm volatile("s_waitcnt lgkmcnt(0)" ::: "memory");
    // 64 rows x 64B (4 chunks); 4 stores/thread, rows 16-granular
    u16* gbase = Oz + ((bb * 16 + hh) * 2048 + tt0) * 64 + d0;
#pragma unroll
    for (int kq = 0; kq < 4; ++kq) {
      const int row = kq * 16 + (lane >> 2), c = lane & 3;
      bf16x8 v = *reinterpret_cast<const bf16x8*>(&ep[row * 36 + c * 8]);
      *reinterpret_cast<bf16x8*>(&gbase[(size_t)row * 64 + c * 8]) = v;
    }
  } else {
    // transposed: LDS layout [32 rows(d)][72]: col = local m (0..63)
#pragma unroll
    for (int i = 0; i < 4; ++i)
#pragma unroll
      for (int j = 0; j < 2; ++j)
#pragma unroll
        for (int r = 0; r < 4; ++r)
          ep[(j * 16 + lq) * 72 + i * 16 + quad * 4 + r] = f2bf(acc[i][j][r]);
    asm volatile("s_waitcnt lgkmcnt(0)" ::: "memory");
    // 32 rows (d) x 128B (8 chunks); 4 stores/thread
    u16* gbase = Oz + ((size_t)(bb * 16 + hh) * 64 + d0) * 2048 + tt0;
#pragma unroll
    for (int kq = 0; kq < 4; ++kq) {
      const int row = kq * 8 + (lane >> 3), c = lane & 7;
      bf16x8 v = *reinterpret_cast<const bf16x8*>(&ep[row * 72 + c * 8]);
      *reinterpret_cast<bf16x8*>(&gbase[(size_t)row * 2048 + c * 8]) = v;
    }
  }
}

// ---------------- Pass C: flash attention, S^T-form, full-rate 16x16x32 PV ----------------
// ROUND-11 EXACT VERSION (best measured: 76.6 us steady, 0 bank conflicts).
// r12's KVBLK=128 regressed (+1.8 us, 4.2M conflicts) -- reverted.
// 8 waves x 32 q/wave, 256-q tile, 2-buffer __syncthreads pipeline, plus:
//   1. Wave-staggered half order (h0 = w&1): at any instant ~half the waves
//      are in ds_read while the others MFMA (FP sum reorder only).
//   2. s_setprio(1) around the MFMA clusters, 0 during the exp/pack stretch.
//
// Key-permuted S^T: for 32-key half `half`, sub-MFMA kg2 reads K row
// key(m) = half*32 + (m>>2)*8 + kg2*4 + (m&3), so each lane's 8 P values
// sit at keys quad*8+{0..7} == the 16x16x32 A-frag layout. PV at full 2xK
// rate; V B-frag one contiguous bf16x8 per dg. Row-sum via
// mfma(pa, ones, Lacc). Palace mask: q-slot = (w&1)*4 + qg*2 + (lq>>3);
// key-slot = half*4 + quad, uniform over the lane's 8 keys.
// LDS swizzle: position = chunk ^ s(row), s(row) = (row&3) | (((row>>3)&1)<<2).
__global__ __launch_bounds__(512, 4) void palace_attn(const u16* __restrict__ Q,
                                                      const u16* __restrict__ K,
                                                      const u16* __restrict__ Vt,
                                                      float* __restrict__ out,
                                                      const float* __restrict__ wptr) {
  const int bh = blockIdx.x, qt = blockIdx.y;
  const int h = bh & 15, b = bh >> 4;
  const size_t base = (size_t)bh * (2048 * 64);

  __shared__ __align__(16) u16 Ks[2][64 * 64];   // [key][d], swizzled 16B chunks
  __shared__ __align__(16) u16 Vs[2][64 * 64];   // [d][key], swizzled 16B chunks

  const int t = threadIdx.x;
  const int w = t >> 6, lane = t & 63, quad = lane >> 4, lq = lane & 15;
  const int lq3 = lq >> 3;
  const int swk = (lq & 3) | (((lq >> 2) & 1) << 2);  // s(row) for permuted K rows
  const int swv = (lq & 3) | (lq3 << 2);              // s(d) for V rows d=dg*16+lq
  const float sig = 1.f / (1.f + __expf(-wptr[0]));
  const float Ci = 0.125f * 1.44269504f;   // intra coeff (scale * log2 e)
  const float Co = Ci * sig;               // inter coeff
  const float MC = 14.4269504f;            // fixed softmax offset: 10 * log2 e

  // palace mask: q-slot = (w&1)*4 + qg*2 + lq3; key-slot = half*4 + quad
  const int qs0 = (w & 1) * 4;
  float cft[2][2];
#pragma unroll
  for (int half = 0; half < 2; ++half)
#pragma unroll
    for (int qg = 0; qg < 2; ++qg)
      cft[half][qg] = (half * 4 + quad == qs0 + qg * 2 + lq3) ? Ci : Co;

  // Q B-frags (16x16x32): B[k=d][n=q], q = qt*256 + w*32 + qg*16 + lq
  bf16x8 qf[2][2];
#pragma unroll
  for (int qg = 0; qg < 2; ++qg)
#pragma unroll
    for (int kc = 0; kc < 2; ++kc)
      qf[qg][kc] = *reinterpret_cast<const bf16x8*>(
          Q + base + (size_t)(qt * 256 + w * 32 + qg * 16 + lq) * 64 + kc * 32 + quad * 8);

  // staging: slot = t (512 threads cover 512 16B slots); row = slot>>3;
  // source chunk = (slot&7) ^ s(row)
  const int row_s = t >> 3;
  const int sr_s = (row_s & 3) | (((row_s >> 3) & 1) << 2);
  const int cl_s = (t & 7) ^ sr_s;
  const int ko = row_s * 64 + cl_s * 8;     // K: [key][64]
  const int vo = row_s * 2048 + cl_s * 8;   // Vt: [d][2048]

  f32x4 O[2][4];
  f32x4 Lacc[2];
#pragma unroll
  for (int qg = 0; qg < 2; ++qg) {
    Lacc[qg] = f32x4{0.f, 0.f, 0.f, 0.f};
#pragma unroll
    for (int dg = 0; dg < 4; ++dg) O[qg][dg] = f32x4{0.f, 0.f, 0.f, 0.f};
  }

  const short oneb = (short)0x3F80;  // bf16 1.0
  const bf16x8 ones8 = {oneb, oneb, oneb, oneb, oneb, oneb, oneb, oneb};

  const int h0 = w & 1;  // wave-staggered half order

  // prologue: stage tile 0 into buffer 0 (1 K + 1 V load per thread)
  {
    const u16* kgp = K + base;
    const u16* vgp = Vt + base;
    async16(kgp + ko, &Ks[0][(w * 64) * 8]);
    async16(vgp + vo, &Vs[0][(w * 64) * 8]);
  }

  for (int kt = 0; kt < 32; ++kt) {
    const int cur = kt & 1;
    __syncthreads();  // drains DMA into buf[cur]; prior reads of buf[cur^1] done
    if (kt < 31) {
      const u16* kgp = K + base + (size_t)(kt + 1) * 4096;
      const u16* vgp = Vt + base + (size_t)(kt + 1) * 64;
      const int nb = cur ^ 1;
      async16(kgp + ko, &Ks[nb][(w * 64) * 8]);
      async16(vgp + vo, &Vs[nb][(w * 64) * 8]);
    }

#pragma unroll
    for (int hx = 0; hx < 2; ++hx) {
      const int half = hx ^ h0;  // waves process halves in opposite order
      // permuted K rows: key = half*32 + (lq>>2)*8 + kg2*4 + (lq&3)
      const int rb = half * 32 + ((lq >> 2) << 3) + (lq & 3);
      bf16x8 kf[2][2];
#pragma unroll
      for (int kg2 = 0; kg2 < 2; ++kg2) {
        const int krow = rb + kg2 * 4;
        kf[kg2][0] = *reinterpret_cast<const bf16x8*>(
            &Ks[cur][krow * 64 + (quad ^ swk) * 8]);          // d chunk = quad
        kf[kg2][1] = *reinterpret_cast<const bf16x8*>(
            &Ks[cur][krow * 64 + ((quad + 4) ^ swk) * 8]);    // d chunk = quad+4
      }

      // V B-frags (16x16x32): B[k=key][n=d], keys half*32+quad*8..+7 contiguous
      bf16x8 vbf[4];
#pragma unroll
      for (int dg = 0; dg < 4; ++dg)
        vbf[dg] = *reinterpret_cast<const bf16x8*>(
            &Vs[cur][(dg * 16 + lq) * 64 + ((half * 4 + quad) ^ swv) * 8]);

#pragma unroll
      for (int qg = 0; qg < 2; ++qg) {
        // S^T[key][q] for the 32-key half: two sub-MFMAs x two d-chunks
        f32x4 z0 = {0.f, 0.f, 0.f, 0.f}, z1 = {0.f, 0.f, 0.f, 0.f};
        __builtin_amdgcn_s_setprio(1);
        z0 = __builtin_amdgcn_mfma_f32_16x16x32_bf16(kf[0][0], qf[qg][0], z0, 0, 0, 0);
        z0 = __builtin_amdgcn_mfma_f32_16x16x32_bf16(kf[0][1], qf[qg][1], z0, 0, 0, 0);
        z1 = __builtin_amdgcn_mfma_f32_16x16x32_bf16(kf[1][0], qf[qg][0], z1, 0, 0, 0);
        z1 = __builtin_amdgcn_mfma_f32_16x16x32_bf16(kf[1][1], qf[qg][1], z1, 0, 0, 0);
        __builtin_amdgcn_s_setprio(0);

        const float cf = cft[half][qg];
        const float p0 = fexp2(__builtin_fmaf(z0[0], cf, -MC));
        const float p1 = fexp2(__builtin_fmaf(z0[1], cf, -MC));
        const float p2 = fexp2(__builtin_fmaf(z0[2], cf, -MC));
        const float p3 = fexp2(__builtin_fmaf(z0[3], cf, -MC));
        const float p4 = fexp2(__builtin_fmaf(z1[0], cf, -MC));
        const float p5 = fexp2(__builtin_fmaf(z1[1], cf, -MC));
        const float p6 = fexp2(__builtin_fmaf(z1[2], cf, -MC));
        const float p7 = fexp2(__builtin_fmaf(z1[3], cf, -MC));

        u32x4 pk;
        pk.x = pk2bf(p0, p1);
        pk.y = pk2bf(p2, p3);
        pk.z = pk2bf(p4, p5);
        pk.w = pk2bf(p6, p7);
        const bf16x8 pa = __builtin_bit_cast(bf16x8, pk);

        // softmax denominator: C reg r = sum_k P[q=qg*16+quad*4+r][k]
        __builtin_amdgcn_s_setprio(1);
        Lacc[qg] = __builtin_amdgcn_mfma_f32_16x16x32_bf16(pa, ones8, Lacc[qg], 0, 0, 0);
#pragma unroll
        for (int dg = 0; dg < 4; ++dg)
          O[qg][dg] = __builtin_amdgcn_mfma_f32_16x16x32_bf16(pa, vbf[dg], O[qg][dg], 0, 0, 0);
        __builtin_amdgcn_s_setprio(0);
      }
    }
  }

  // epilogue: O C-layout: q = qg*16+quad*4+r (row), d = dg*16+lq (col);
  // Lacc has the matching row layout -- no cross-lane reduce needed.
#pragma unroll
  for (int qg = 0; qg < 2; ++qg) {
#pragma unroll
    for (int r = 0; r < 4; ++r) {
      const float iv = 1.f / Lacc[qg][r];
      const size_t trow = (size_t)(qt * 256 + w * 32 + qg * 16 + quad * 4 + r);
      float* op = out + ((size_t)b * 2048 + trow) * 1024 + h * 64 + lq;
#pragma unroll
      for (int dg = 0; dg < 4; ++dg) op[dg * 16] = O[qg][dg][r] * iv;
    }
  }
}

extern "C" void kernel_launch(void* const* d_in, const int* in_sizes, int n_in,
                              void* d_out, int out_size, void* d_ws, size_t ws_size,
                              hipStream_t stream) {
  (void)in_sizes; (void)n_in; (void)out_size; (void)ws_size;
  const float* x = (const float*)d_in[0];
  const float* Wq = (const float*)d_in[1];
  const float* Wk = (const float*)d_in[2];
  const float* Wv = (const float*)d_in[3];
  const float* wip = (const float*)d_in[4];
  float* out = (float*)d_out;

  u16* xb = (u16*)d_ws;
  u16* wb = xb + 8388608;
  u16* qb = wb + 3145728;
  u16* kb = qb + 8388608;
  u16* vb = kb + 8388608;   // holds V^T [B][H][64][2048]

  cvt_all<<<11264, 256, 0, stream>>>(x, Wq, Wk, Wv, xb, wb);
  qkv_gemm<<<dim3(64, 8, 3), 512, 0, stream>>>(xb, wb, qb);
  palace_attn<<<dim3(64, 8, 1), 512, 0, stream>>>(qb, kb, vb, out, wip);
}

// Round 14
// 211.792 us; speedup vs baseline: 1.0242x; 1.0242x over previous
//
#include <hip/hip_runtime.h>

typedef unsigned short u16;
typedef unsigned int u32;
typedef short bf16x8 __attribute__((ext_vector_type(8)));
typedef float f32x4 __attribute__((ext_vector_type(4)));
typedef u32 u32x4 __attribute__((ext_vector_type(4)));

#define AS_GLOBAL __attribute__((address_space(1)))
#define AS_LDS __attribute__((address_space(3)))

__device__ __forceinline__ void async16(const void* g, void* l) {
  __builtin_amdgcn_global_load_lds((const AS_GLOBAL u32*)g, (AS_LDS u32*)l, 16, 0, 0);
}

__device__ __forceinline__ u16 f2bf(float f) {
  u32 u = __builtin_bit_cast(u32, f);
  u += 0x7FFFu + ((u >> 16) & 1u);   // RNE
  return (u16)(u >> 16);
}

__device__ __forceinline__ u32 pk2bf(float lo, float hi) {
  return __builtin_amdgcn_perm(__builtin_bit_cast(u32, hi),
                               __builtin_bit_cast(u32, lo), 0x07060302u);
}

__device__ __forceinline__ float fexp2(float x) {
#if __has_builtin(__builtin_amdgcn_exp2f)
  return __builtin_amdgcn_exp2f(x);
#else
  return exp2f(x);
#endif
}

// ---------------- Pass A: all four f32 -> bf16 converts in one launch ----------------
// At HBM roofline for its traffic (69 MB ~= 11-12 us).
__global__ __launch_bounds__(256) void cvt_all(const float* __restrict__ x,
                                               const float* __restrict__ wq,
                                               const float* __restrict__ wk,
                                               const float* __restrict__ wv,
                                               u16* __restrict__ xb,
                                               u16* __restrict__ wb) {
  const int blk = blockIdx.x;
  const float* src;
  u16* dst;
  int i;
  if (blk < 8192) {
    src = x; dst = xb; i = blk * 256 + threadIdx.x;
  } else if (blk < 9216) {
    src = wq; dst = wb; i = (blk - 8192) * 256 + threadIdx.x;
  } else if (blk < 10240) {
    src = wk; dst = wb + 1048576; i = (blk - 9216) * 256 + threadIdx.x;
  } else {
    src = wv; dst = wb + 2097152; i = (blk - 10240) * 256 + threadIdx.x;
  }
  float4 f = reinterpret_cast<const float4*>(src)[i];
  ushort4 o;
  o.x = f2bf(f.x); o.y = f2bf(f.y); o.z = f2bf(f.z); o.w = f2bf(f.w);
  reinterpret_cast<ushort4*>(dst)[i] = o;
}

// ---------------- Pass B: QKV projection GEMM (C = X * W^T) ----------------
// ROUND-7 PROVEN 4-WAVE VERSION (present in both best totals 211.7/212.3).
// r12/r13 same-attn comparison showed the 8-wave split is ~4.6 us WORSE
// (212.3 vs 216.9 with identical attn) -- extra per-CU LDS-read traffic and
// halved per-wave MFMA amortization cost more than the occupancy gained.
// K-loop: 256 thr, 2x2 waves of 64x64, BK=64, double-buffered LDS, one
// __syncthreads per k-tile, conflict-free chunk-XOR swizzle. Epilogue stages
// C through LDS and emits 8 x global_store_dwordx4 per thread (the r7 win:
// scalar-scatter stores were ~30 us of hidden cost).
// grid: x = m-tile (64), y = n-tile (8), z = matrix (3)
// z=0 (Q), z=1 (K): out [B][H][T][64]; z=2 (V): out TRANSPOSED [B][H][64][T]
__global__ __launch_bounds__(256, 2) void qkv_gemm(const u16* __restrict__ X,
                                                   const u16* __restrict__ W,
                                                   u16* __restrict__ O) {
  const int z = blockIdx.z;
  const u16* Wz = W + (size_t)z * (1024 * 1024);
  u16* Oz = O + (size_t)z * (8192 * 1024);

  // unified 64KB: SMEM[0..1] = A dbuf, SMEM[2..3] = B dbuf; epilogue reuses
  // SMEM[w] as wave-private staging (8192 u16 each >= 64*80).
  __shared__ __align__(16) u16 SMEM[4][8192];

  const int t = threadIdx.x;
  const int lane = t & 63, w = t >> 6, quad = lane >> 4, lq = lane & 15;
  const int wm = (w >> 1) * 64, wn = (w & 1) * 64;
  const int sw = lq & 7;
  const size_t m0 = (size_t)blockIdx.x * 128;
  const int n0 = blockIdx.y * 128;

  // staging source offsets (u16 units): slot -> (row, pre-swizzled chunk)
  int off[4];
#pragma unroll
  for (int j = 0; j < 4; ++j) {
    const int s = j * 256 + t, row = s >> 3, c = (s & 7) ^ (row & 7);
    off[j] = row * 1024 + c * 8;
  }
  const u16* gA = X + m0 * 1024;
  const u16* gB = Wz + (size_t)n0 * 1024;

  f32x4 acc[4][4];
#pragma unroll
  for (int i = 0; i < 4; ++i)
#pragma unroll
    for (int j = 0; j < 4; ++j) acc[i][j] = f32x4{0.f, 0.f, 0.f, 0.f};

  // 8 gload_lds(16B)/thread stages one 128x64 A panel + 128x64 B panel
  auto stage = [&](int kt, int nb) {
    const u16* ga = gA + kt * 64;
    const u16* gb = gB + kt * 64;
#pragma unroll
    for (int j = 0; j < 4; ++j)
      async16(ga + off[j], &SMEM[nb][(j * 256 + t) * 8]);
#pragma unroll
    for (int j = 0; j < 4; ++j)
      async16(gb + off[j], &SMEM[2 + nb][(j * 256 + t) * 8]);
  };

  // prologue: stage tile 0 into buffer 0
  stage(0, 0);

  for (int kt = 0; kt < 16; ++kt) {
    const int cur = kt & 1;
    __syncthreads();                    // tile kt resident; buf[cur^1] free
    if (kt < 15) stage(kt + 1, cur ^ 1);

    bf16x8 Af[4][2], Bf[4][2];
#pragma unroll
    for (int i = 0; i < 4; ++i)
#pragma unroll
      for (int ks = 0; ks < 2; ++ks) {
        Af[i][ks] = *reinterpret_cast<const bf16x8*>(
            &SMEM[cur][(wm + i * 16 + lq) * 64 + ((ks * 4 + quad) ^ sw) * 8]);
        Bf[i][ks] = *reinterpret_cast<const bf16x8*>(
            &SMEM[2 + cur][(wn + i * 16 + lq) * 64 + ((ks * 4 + quad) ^ sw) * 8]);
      }
#pragma unroll
    for (int i = 0; i < 4; ++i)
#pragma unroll
      for (int j = 0; j < 4; ++j) {
        acc[i][j] = __builtin_amdgcn_mfma_f32_16x16x32_bf16(Af[i][0], Bf[j][0], acc[i][j], 0, 0, 0);
        acc[i][j] = __builtin_amdgcn_mfma_f32_16x16x32_bf16(Af[i][1], Bf[j][1], acc[i][j], 0, 0, 0);
      }
  }

  // ---- wide-store epilogue ----
  __syncthreads();                      // all LDS reads of the main loop done
  u16* ep = &SMEM[w][0];                // wave-private region, layout [64][80]
  if (z != 2) {
    // LDS row = local m (0..63), col = local n (0..63)
#pragma unroll
    for (int i = 0; i < 4; ++i)
#pragma unroll
      for (int j = 0; j < 4; ++j)
#pragma unroll
        for (int r = 0; r < 4; ++r)
          ep[(i * 16 + quad * 4 + r) * 80 + j * 16 + lq] = f2bf(acc[i][j][r]);
  } else {
    // transposed: LDS row = local n (=d), col = local m (=t)
#pragma unroll
    for (int i = 0; i < 4; ++i)
#pragma unroll
      for (int j = 0; j < 4; ++j)
#pragma unroll
        for (int r = 0; r < 4; ++r)
          ep[(j * 16 + lq) * 80 + i * 16 + quad * 4 + r] = f2bf(acc[i][j][r]);
  }
  asm volatile("s_waitcnt lgkmcnt(0)" ::: "memory");  // own-wave writes visible

  const int r8 = lane >> 3, c8 = lane & 7;            // 8 rows x 8 chunks
  const size_t ms = m0 + wm;
  const size_t bb = ms >> 11, tt0 = ms & 2047;
  const int hh = (n0 + wn) >> 6;
  if (z != 2) {
    // wave tile = contiguous 8KB at ((bb*16+hh)*2048 + tt0)*64
    u16* gbase = Oz + ((bb * 16 + hh) * 2048 + tt0) * 64;
#pragma unroll
    for (int kq = 0; kq < 8; ++kq) {
      const int row = kq * 8 + r8;
      bf16x8 v = *reinterpret_cast<const bf16x8*>(&ep[row * 80 + c8 * 8]);
      *reinterpret_cast<bf16x8*>(&gbase[(size_t)row * 64 + c8 * 8]) = v;
    }
  } else {
    // wave tile = 64 rows (d) of 128B at stride 4KB
    u16* gbase = Oz + ((size_t)(bb * 16 + hh) * 64) * 2048 + tt0;
#pragma unroll
    for (int kq = 0; kq < 8; ++kq) {
      const int row = kq * 8 + r8;
      bf16x8 v = *reinterpret_cast<const bf16x8*>(&ep[row * 80 + c8 * 8]);
      *reinterpret_cast<bf16x8*>(&gbase[(size_t)row * 2048 + c8 * 8]) = v;
    }
  }
}

// ---------------- Pass C: flash attention, S^T-form, full-rate 16x16x32 PV ----------------
// ROUND-11 EXACT VERSION (best measured: 76.3-76.6 us steady, 0 bank
// conflicts, reproduced across three runs).
// 8 waves x 32 q/wave, 256-q tile, 2-buffer __syncthreads pipeline, plus:
//   1. Wave-staggered half order (h0 = w&1): at any instant ~half the waves
//      are in ds_read while the others MFMA (FP sum reorder only).
//   2. s_setprio(1) around the MFMA clusters, 0 during the exp/pack stretch.
//
// Key-permuted S^T: for 32-key half `half`, sub-MFMA kg2 reads K row
// key(m) = half*32 + (m>>2)*8 + kg2*4 + (m&3), so each lane's 8 P values
// sit at keys quad*8+{0..7} == the 16x16x32 A-frag layout. PV at full 2xK
// rate; V B-frag one contiguous bf16x8 per dg. Row-sum via
// mfma(pa, ones, Lacc). Palace mask: q-slot = (w&1)*4 + qg*2 + (lq>>3);
// key-slot = half*4 + quad, uniform over the lane's 8 keys.
// LDS swizzle: position = chunk ^ s(row), s(row) = (row&3) | (((row>>3)&1)<<2).
__global__ __launch_bounds__(512, 4) void palace_attn(const u16* __restrict__ Q,
                                                      const u16* __restrict__ K,
                                                      const u16* __restrict__ Vt,
                                                      float* __restrict__ out,
                                                      const float* __restrict__ wptr) {
  const int bh = blockIdx.x, qt = blockIdx.y;
  const int h = bh & 15, b = bh >> 4;
  const size_t base = (size_t)bh * (2048 * 64);

  __shared__ __align__(16) u16 Ks[2][64 * 64];   // [key][d], swizzled 16B chunks
  __shared__ __align__(16) u16 Vs[2][64 * 64];   // [d][key], swizzled 16B chunks

  const int t = threadIdx.x;
  const int w = t >> 6, lane = t & 63, quad = lane >> 4, lq = lane & 15;
  const int lq3 = lq >> 3;
  const int swk = (lq & 3) | (((lq >> 2) & 1) << 2);  // s(row) for permuted K rows
  const int swv = (lq & 3) | (lq3 << 2);              // s(d) for V rows d=dg*16+lq
  const float sig = 1.f / (1.f + __expf(-wptr[0]));
  const float Ci = 0.125f * 1.44269504f;   // intra coeff (scale * log2 e)
  const float Co = Ci * sig;               // inter coeff
  const float MC = 14.4269504f;            // fixed softmax offset: 10 * log2 e

  // palace mask: q-slot = (w&1)*4 + qg*2 + lq3; key-slot = half*4 + quad
  const int qs0 = (w & 1) * 4;
  float cft[2][2];
#pragma unroll
  for (int half = 0; half < 2; ++half)
#pragma unroll
    for (int qg = 0; qg < 2; ++qg)
      cft[half][qg] = (half * 4 + quad == qs0 + qg * 2 + lq3) ? Ci : Co;

  // Q B-frags (16x16x32): B[k=d][n=q], q = qt*256 + w*32 + qg*16 + lq
  bf16x8 qf[2][2];
#pragma unroll
  for (int qg = 0; qg < 2; ++qg)
#pragma unroll
    for (int kc = 0; kc < 2; ++kc)
      qf[qg][kc] = *reinterpret_cast<const bf16x8*>(
          Q + base + (size_t)(qt * 256 + w * 32 + qg * 16 + lq) * 64 + kc * 32 + quad * 8);

  // staging: slot = t (512 threads cover 512 16B slots); row = slot>>3;
  // source chunk = (slot&7) ^ s(row)
  const int row_s = t >> 3;
  const int sr_s = (row_s & 3) | (((row_s >> 3) & 1) << 2);
  const int cl_s = (t & 7) ^ sr_s;
  const int ko = row_s * 64 + cl_s * 8;     // K: [key][64]
  const int vo = row_s * 2048 + cl_s * 8;   // Vt: [d][2048]

  f32x4 O[2][4];
  f32x4 Lacc[2];
#pragma unroll
  for (int qg = 0; qg < 2; ++qg) {
    Lacc[qg] = f32x4{0.f, 0.f, 0.f, 0.f};
#pragma unroll
    for (int dg = 0; dg < 4; ++dg) O[qg][dg] = f32x4{0.f, 0.f, 0.f, 0.f};
  }

  const short oneb = (short)0x3F80;  // bf16 1.0
  const bf16x8 ones8 = {oneb, oneb, oneb, oneb, oneb, oneb, oneb, oneb};

  const int h0 = w & 1;  // wave-staggered half order

  // prologue: stage tile 0 into buffer 0 (1 K + 1 V load per thread)
  {
    const u16* kgp = K + base;
    const u16* vgp = Vt + base;
    async16(kgp + ko, &Ks[0][(w * 64) * 8]);
    async16(vgp + vo, &Vs[0][(w * 64) * 8]);
  }

  for (int kt = 0; kt < 32; ++kt) {
    const int cur = kt & 1;
    __syncthreads();  // drains DMA into buf[cur]; prior reads of buf[cur^1] done
    if (kt < 31) {
      const u16* kgp = K + base + (size_t)(kt + 1) * 4096;
      const u16* vgp = Vt + base + (size_t)(kt + 1) * 64;
      const int nb = cur ^ 1;
      async16(kgp + ko, &Ks[nb][(w * 64) * 8]);
      async16(vgp + vo, &Vs[nb][(w * 64) * 8]);
    }

#pragma unroll
    for (int hx = 0; hx < 2; ++hx) {
      const int half = hx ^ h0;  // waves process halves in opposite order
      // permuted K rows: key = half*32 + (lq>>2)*8 + kg2*4 + (lq&3)
      const int rb = half * 32 + ((lq >> 2) << 3) + (lq & 3);
      bf16x8 kf[2][2];
#pragma unroll
      for (int kg2 = 0; kg2 < 2; ++kg2) {
        const int krow = rb + kg2 * 4;
        kf[kg2][0] = *reinterpret_cast<const bf16x8*>(
            &Ks[cur][krow * 64 + (quad ^ swk) * 8]);          // d chunk = quad
        kf[kg2][1] = *reinterpret_cast<const bf16x8*>(
            &Ks[cur][krow * 64 + ((quad + 4) ^ swk) * 8]);    // d chunk = quad+4
      }

      // V B-frags (16x16x32): B[k=key][n=d], keys half*32+quad*8..+7 contiguous
      bf16x8 vbf[4];
#pragma unroll
      for (int dg = 0; dg < 4; ++dg)
        vbf[dg] = *reinterpret_cast<const bf16x8*>(
            &Vs[cur][(dg * 16 + lq) * 64 + ((half * 4 + quad) ^ swv) * 8]);

#pragma unroll
      for (int qg = 0; qg < 2; ++qg) {
        // S^T[key][q] for the 32-key half: two sub-MFMAs x two d-chunks
        f32x4 z0 = {0.f, 0.f, 0.f, 0.f}, z1 = {0.f, 0.f, 0.f, 0.f};
        __builtin_amdgcn_s_setprio(1);
        z0 = __builtin_amdgcn_mfma_f32_16x16x32_bf16(kf[0][0], qf[qg][0], z0, 0, 0, 0);
        z0 = __builtin_amdgcn_mfma_f32_16x16x32_bf16(kf[0][1], qf[qg][1], z0, 0, 0, 0);
        z1 = __builtin_amdgcn_mfma_f32_16x16x32_bf16(kf[1][0], qf[qg][0], z1, 0, 0, 0);
        z1 = __builtin_amdgcn_mfma_f32_16x16x32_bf16(kf[1][1], qf[qg][1], z1, 0, 0, 0);
        __builtin_amdgcn_s_setprio(0);

        const float cf = cft[half][qg];
        const float p0 = fexp2(__builtin_fmaf(z0[0], cf, -MC));
        const float p1 = fexp2(__builtin_fmaf(z0[1], cf, -MC));
        const float p2 = fexp2(__builtin_fmaf(z0[2], cf, -MC));
        const float p3 = fexp2(__builtin_fmaf(z0[3], cf, -MC));
        const float p4 = fexp2(__builtin_fmaf(z1[0], cf, -MC));
        const float p5 = fexp2(__builtin_fmaf(z1[1], cf, -MC));
        const float p6 = fexp2(__builtin_fmaf(z1[2], cf, -MC));
        const float p7 = fexp2(__builtin_fmaf(z1[3], cf, -MC));

        u32x4 pk;
        pk.x = pk2bf(p0, p1);
        pk.y = pk2bf(p2, p3);
        pk.z = pk2bf(p4, p5);
        pk.w = pk2bf(p6, p7);
        const bf16x8 pa = __builtin_bit_cast(bf16x8, pk);

        // softmax denominator: C reg r = sum_k P[q=qg*16+quad*4+r][k]
        __builtin_amdgcn_s_setprio(1);
        Lacc[qg] = __builtin_amdgcn_mfma_f32_16x16x32_bf16(pa, ones8, Lacc[qg], 0, 0, 0);
#pragma unroll
        for (int dg = 0; dg < 4; ++dg)
          O[qg][dg] = __builtin_amdgcn_mfma_f32_16x16x32_bf16(pa, vbf[dg], O[qg][dg], 0, 0, 0);
        __builtin_amdgcn_s_setprio(0);
      }
    }
  }

  // epilogue: O C-layout: q = qg*16+quad*4+r (row), d = dg*16+lq (col);
  // Lacc has the matching row layout -- no cross-lane reduce needed.
#pragma unroll
  for (int qg = 0; qg < 2; ++qg) {
#pragma unroll
    for (int r = 0; r < 4; ++r) {
      const float iv = 1.f / Lacc[qg][r];
      const size_t trow = (size_t)(qt * 256 + w * 32 + qg * 16 + quad * 4 + r);
      float* op = out + ((size_t)b * 2048 + trow) * 1024 + h * 64 + lq;
#pragma unroll
      for (int dg = 0; dg < 4; ++dg) op[dg * 16] = O[qg][dg][r] * iv;
    }
  }
}

extern "C" void kernel_launch(void* const* d_in, const int* in_sizes, int n_in,
                              void* d_out, int out_size, void* d_ws, size_t ws_size,
                              hipStream_t stream) {
  (void)in_sizes; (void)n_in; (void)out_size; (void)ws_size;
  const float* x = (const float*)d_in[0];
  const float* Wq = (const float*)d_in[1];
  const float* Wk = (const float*)d_in[2];
  const float* Wv = (const float*)d_in[3];
  const float* wip = (const float*)d_in[4];
  float* out = (float*)d_out;

  u16* xb = (u16*)d_ws;
  u16* wb = xb + 8388608;
  u16* qb = wb + 3145728;
  u16* kb = qb + 8388608;
  u16* vb = kb + 8388608;   // holds V^T [B][H][64][2048]

  cvt_all<<<11264, 256, 0, stream>>>(x, Wq, Wk, Wv, xb, wb);
  qkv_gemm<<<dim3(64, 8, 3), 256, 0, stream>>>(xb, wb, qb);
  palace_attn<<<dim3(64, 8, 1), 512, 0, stream>>>(qb, kb, vb, out, wip);
}